// Round 5
// baseline (103.702 us; speedup 1.0000x reference)
//
#include <hip/hip_runtime.h>
#include <math.h>

typedef _Float16 f16x8 __attribute__((ext_vector_type(8)));
typedef float f32x4 __attribute__((ext_vector_type(4)));
typedef unsigned int u32;
typedef unsigned long long u64;

#define NBATCH 32
#define CIN    64
#define COUT   192
#define HWD    56
#define KR     4
#define NKQ    14

// ---- LDS layout (dynamic, 92160 B) ----
#define EHOFF   0              // 72 rows * 128 B
#define ELOFF   9216
#define BOFF    18432          // 6 bufs * 12288
#define BBUF    12288
#define XOFF    18432          // overlaps B ring; consumed before first STAGE
#define XSTRIDE 88
#define LDS_TOTAL 92160

// ws layout
#define WS_BT_OFF 0
#define WS_W_OFF  1024

#define SBAR()  do { __builtin_amdgcn_s_barrier(); asm volatile("" ::: "memory"); } while(0)
#define WAITL() asm volatile("s_waitcnt lgkmcnt(0)" ::: "memory")
#define WAITV4() asm volatile("s_waitcnt vmcnt(4) lgkmcnt(0)" ::: "memory")
#define WAITV2() asm volatile("s_waitcnt vmcnt(2) lgkmcnt(0)" ::: "memory")
#define WAITV0() asm volatile("s_waitcnt vmcnt(0) lgkmcnt(0)" ::: "memory")

// ---------------- Kernel 1: wave-parallel Householder QR (f64) + fp16-range flag ----------------
__device__ __forceinline__ double wsum(double v) {
    #pragma unroll
    for (int m = 32; m >= 1; m >>= 1) v += __shfl_xor(v, m);
    return v;
}

__global__ void compute_bt_kernel(float* __restrict__ bt) {
    const int lane = threadIdx.x;
    const double ATd[5][7] = {
        {1,1,1,1,1,1,0},{0,1,-1,2,-2,3,0},{0,1,1,4,4,9,0},{0,1,-1,8,-8,27,0},{0,1,1,16,16,81,1}};
    const double pts[6] = {0.0,1.0,-1.0,2.0,-2.0,3.0};

    double Mr[7], Tr[7];
    #pragma unroll
    for (int c = 0; c < 7; ++c) { Mr[c] = 0.0; Tr[c] = 0.0; }
    if (lane < 15) {
        const int p = lane / 5, u = lane % 5;
        #pragma unroll
        for (int v = 0; v < 7; ++v) {
            double gg = (v < 6) ? ((p == 0) ? 1.0 : (p == 1) ? pts[v] : pts[v]*pts[v])
                                : ((p == 2) ? 1.0 : 0.0);
            Mr[v] = ATd[u][v] * gg;
        }
        #pragma unroll
        for (int c = 0; c < 7; ++c) Tr[c] = (c == u + p) ? 1.0 : 0.0;
    }

    #pragma unroll
    for (int j = 0; j < 7; ++j) {
        double mj = Mr[j];
        double sig = wsum((lane >= j && lane < 15) ? mj*mj : 0.0);
        double nrm = sqrt(sig);
        double ajj = __shfl(Mr[j], j);
        double alpha = (ajj > 0.0) ? -nrm : nrm;
        double vi = 0.0;
        if (lane == j) vi = ajj - alpha;
        else if (lane > j && lane < 15) vi = mj;
        double vtv = sig - 2.0*alpha*ajj + alpha*alpha;
        double tau = (vtv > 1e-300) ? (2.0 / vtv) : 0.0;
        #pragma unroll
        for (int c = 0; c < 7; ++c) {
            if (c >= j) {
                double s = wsum(vi * Mr[c]) * tau;
                Mr[c] -= s * vi;
            }
        }
        #pragma unroll
        for (int c = 0; c < 7; ++c) {
            double s = wsum(vi * Tr[c]) * tau;
            Tr[c] -= s * vi;
        }
        if (lane == j) Mr[j] = alpha;
        if (lane > j)  Mr[j] = 0.0;
    }

    __shared__ double Rs[7][7], Ts[7][7];
    if (lane < 7) {
        #pragma unroll
        for (int c = 0; c < 7; ++c) { Rs[lane][c] = Mr[c]; Ts[lane][c] = Tr[c]; }
    }
    __syncthreads();
    const int cc = (lane < 7) ? lane : 0;
    double xs[7];
    #pragma unroll
    for (int i = 6; i >= 0; --i) {
        double s = Ts[i][cc];
        #pragma unroll
        for (int k2 = 6; k2 > i; --k2) s -= Rs[i][k2] * xs[k2];
        xs[i] = s / Rs[i][i];
    }
    if (lane < 7) {
        #pragma unroll
        for (int i = 0; i < 7; ++i) bt[i*7 + lane] = (float)xs[i];
    }
    // fp16-single-plane feasibility: max_v sum_w |BT[v][w]| * 128 <= 2048 ?
    double rs[7];
    #pragma unroll
    for (int v = 0; v < 7; ++v)
        rs[v] = wsum((lane < 7) ? fabs(xs[v]) : 0.0);
    if (lane == 0) {
        double mb = 0.0;
        #pragma unroll
        for (int v = 0; v < 7; ++v) mb = fmax(mb, rs[v]);
        bt[49] = (mb * 128.0 <= 2048.0) ? 1.f : 0.f;
    }
}

// ---------------- Kernel 2: weight transform -> fp16 W[v][o][r][c] ----------------
__global__ void wt16_kernel(const float* __restrict__ w, _Float16* __restrict__ W) {
    int idx = blockIdx.x*256 + threadIdx.x;
    if (idx >= 7*COUT*3*CIN) return;
    int c = idx & 63;
    int r = (idx >> 6) % 3;
    int o = (idx / (64*3)) % COUT;
    int v = idx / (64*3*COUT);
    const float* wp = w + (((size_t)o*CIN + c)*3 + r)*3;
    const float Gf[7][3] = {{1,0,0},{1,1,1},{1,-1,1},{1,2,4},{1,-2,4},{1,3,9},{0,0,1}};
    float val = wp[0]*Gf[v][0] + wp[1]*Gf[v][1] + wp[2]*Gf[v][2];
    val = rintf(val);
    val = fminf(fmaxf(val, -32768.f), 32767.f);   // |val| <= 1664: exact fp16
    W[idx] = (_Float16)val;
}

// ---------------- Kernel 3: fused E-transform + MFMA GEMM + AT + epilogue ----------------
__device__ __forceinline__ void gload16(const void* g, void* l) {
    __builtin_amdgcn_global_load_lds((const __attribute__((address_space(1))) void*)g,
                                     (__attribute__((address_space(3))) void*)l, 16, 0, 0);
}

__global__ __launch_bounds__(768, 3)
void main_kernel(const float* __restrict__ x, const _Float16* __restrict__ W,
                 const float* __restrict__ bt,
                 const float* __restrict__ alpha, const float* __restrict__ beta,
                 const float* __restrict__ sfp, const float* __restrict__ sop,
                 float* __restrict__ out)
{
    extern __shared__ char lds[];
    const int kq = blockIdx.x, n = blockIdx.y, k0 = kq*KR;
    const int tid = threadIdx.x;
    const int wid = tid >> 6, lane = tid & 63, l15 = lane & 15, g = lane >> 4;
    const int mg = wid >> 2, ng = wid & 3;
    const bool dual = (bt[49] < 0.5f);

    const int st_o = tid >> 2, st_q = tid & 3;
    auto STAGE = [&](int S){
        int v = S/6, rem = S%6, rr = rem>>1, ch = rem&1;
        const _Float16* src = W + (((v*COUT + st_o)*3 + rr) << 6) + ch*32 + st_q*8;
        gload16(src, lds + BOFF + (S%6)*BBUF + tid*16);
    };

    // ---- stage x rows (k0-1 .. k0+4) as biased u8 into LDS [6][64][88] (overlaps B ring) ----
    #pragma unroll
    for (int j = 0; j < 7; ++j) {
        int idx = j*768 + tid;                 // < 5376 = 6*64*14
        int krow = idx / 896, rem = idx - krow*896;
        int c = rem / 14, col4 = rem - c*14;
        int xr = k0 + krow - 1;
        u32 bword = 0x80808080u;
        if (xr >= 0 && xr < HWD) {
            const float4 vx = *(const float4*)(x + (((size_t)(n*CIN + c))*HWD + xr)*HWD + col4*4);
            u32 b0 = (u32)(int)(vx.x + 128.f);
            u32 b1 = (u32)(int)(vx.y + 128.f);
            u32 b2 = (u32)(int)(vx.z + 128.f);
            u32 b3 = (u32)(int)(vx.w + 128.f);
            bword = b0 | (b1 << 8) | (b2 << 16) | (b3 << 24);
        }
        *(u32*)(lds + XOFF + (krow*64 + c)*XSTRIDE + 4 + col4*4) = bword;
    }
    #pragma unroll
    for (int jj = 0; jj < 4; ++jj) {           // pads: bytes 0..3 and 60..87 per (krow,c)
        int p = jj*768 + tid;                  // < 3072
        int pr = p >> 3, ws = p & 7;
        int krow = pr >> 6, c = pr & 63;
        int wb = (ws == 0) ? 0 : 56 + ws*4;
        *(u32*)(lds + XOFF + (krow*64 + c)*XSTRIDE + wb) = 0x80808080u;
    }
    __syncthreads();

    // ---- unpack per-thread x window (t = wid, c = lane) into registers ----
    float xf[6][7];
    {
        const int ofs = (5*wid + 3) & 7;
        const int a0  = (5*wid + 3) & ~7;
        const u32 qsel = (u32)(ofs >> 2);
        const u32 r = (u32)((ofs & 3) * 8);
        #pragma unroll
        for (int krow = 0; krow < 6; ++krow) {
            const char* pb = lds + XOFF + (krow*64 + lane)*XSTRIDE + a0;
            uint2 A2 = *(const uint2*)pb;
            uint2 B2 = *(const uint2*)(pb + 8);
            u32 d0 = A2.x, d1 = A2.y, d2 = B2.x, d3 = B2.y;
            u32 e0 = qsel ? d1 : d0, e1 = qsel ? d2 : d1, e2 = qsel ? d3 : d2;
            u64 lo = (((u64)e1 << 32) | e0) >> r;
            u64 hi = (((u64)e2 << 32) | e1) >> r;
            u32 Aw = (u32)lo, Bw = (u32)hi;
            xf[krow][0] = (float)(Aw & 255u);
            xf[krow][1] = (float)((Aw >> 8) & 255u);
            xf[krow][2] = (float)((Aw >> 16) & 255u);
            xf[krow][3] = (float)(Aw >> 24);
            xf[krow][4] = (float)(Bw & 255u);
            xf[krow][5] = (float)((Bw >> 8) & 255u);
            xf[krow][6] = (float)((Bw >> 16) & 255u);
        }
    }
    __syncthreads();            // X region free; B ring may now be written

    // prologue: fill 6-buffer ring (steps 0..5)
    STAGE(0); STAGE(1); STAGE(2); STAGE(3); STAGE(4); STAGE(5);

    f32x4 mv[3], yu[5][3];
    #pragma unroll
    for (int i = 0; i < 3; ++i) mv[i] = f32x4{0.f,0.f,0.f,0.f};
    #pragma unroll
    for (int u = 0; u < 5; ++u)
        #pragma unroll
        for (int i = 0; i < 3; ++i) yu[u][i] = f32x4{0.f,0.f,0.f,0.f};

    const float ATc[5][7] = {
        {1,1,1,1,1,1,0},{0,1,-1,2,-2,3,0},{0,1,1,4,4,9,0},{0,1,-1,8,-8,27,0},{0,1,1,16,16,81,1}};

    const int boff0 = (ng*48 +  0 + l15)*64 + g*16;
    const int boff1 = (ng*48 + 16 + l15)*64 + g*16;
    const int boff2 = (ng*48 + 32 + l15)*64 + g*16;

    #pragma unroll
    for (int v = 0; v < 7; ++v) {
        // fold previous v's mv into yu (registers only)
        if (v > 0) {
            #pragma unroll
            for (int u = 0; u < 5; ++u) {
                const float a = ATc[u][v-1];
                if (a != 0.f) {
                    #pragma unroll
                    for (int fi = 0; fi < 3; ++fi) yu[u][fi] += a * mv[fi];
                }
            }
            #pragma unroll
            for (int fi = 0; fi < 3; ++fi) mv[fi] = f32x4{0.f,0.f,0.f,0.f};
        }

        SBAR();   // pre-E: all waves past previous phase's reads (reads retire before MFMA/barrier)

        // E-compute for this v: rows krow*12 + wid, col = lane
        {
            const float b0 = bt[v*7+0], b1 = bt[v*7+1], b2 = bt[v*7+2], b3 = bt[v*7+3];
            const float b4 = bt[v*7+4], b5 = bt[v*7+5], b6 = bt[v*7+6];
            const float einit = -128.f * (b0+b1+b2+b3+b4+b5+b6);
            #pragma unroll
            for (int krow = 0; krow < 6; ++krow) {
                float e = einit;
                e = fmaf(b0, xf[krow][0], e);
                e = fmaf(b1, xf[krow][1], e);
                e = fmaf(b2, xf[krow][2], e);
                e = fmaf(b3, xf[krow][3], e);
                e = fmaf(b4, xf[krow][4], e);
                e = fmaf(b5, xf[krow][5], e);
                e = fmaf(b6, xf[krow][6], e);
                e = rintf(e);
                e = fminf(fmaxf(e, -32768.f), 32767.f);
                const int row = krow*12 + wid;
                const int sbyte = ((((lane>>3) ^ (row&7)) << 4) | ((lane&7) << 1));
                if (dual) {
                    float ehs = rintf(e * (1.f/2048.f)) * 2048.f;
                    float el  = e - ehs;
                    *(_Float16*)(lds + EHOFF + row*128 + sbyte) = (_Float16)ehs;
                    *(_Float16*)(lds + ELOFF + row*128 + sbyte) = (_Float16)el;
                } else {
                    *(_Float16*)(lds + EHOFF + row*128 + sbyte) = (_Float16)e;
                }
            }
        }

        // 3 fat phases (K=64 each) for this v
        #pragma unroll
        for (int p = 0; p < 3; ++p) {
            const int S = v*6 + 2*p;
            // own-loads wait (also drains E ds_writes at p==0), then barrier
            if (S == 0)       { WAITV4(); }
            else if (S == 40) { WAITV0(); }
            else              { WAITV2(); }
            SBAR();
            // prefetch 2 phases ahead (buffers provably free: their readers pre-barrier)
            if (S >= 2) {
                if (S + 4 <= 41) STAGE(S + 4);
                if (S + 5 <= 41) STAGE(S + 5);
            }
            // reads: A row rr=p, both 32-ch halves; B from two ring bufs
            const char* bb0 = lds + BOFF + (S % 6)*BBUF;
            const char* bb1 = lds + BOFF + ((S + 1) % 6)*BBUF;
            f16x8 b00 = *(const f16x8*)(bb0 + boff0);
            f16x8 b01 = *(const f16x8*)(bb0 + boff1);
            f16x8 b02 = *(const f16x8*)(bb0 + boff2);
            f16x8 b10 = *(const f16x8*)(bb1 + boff0);
            f16x8 b11 = *(const f16x8*)(bb1 + boff1);
            f16x8 b12 = *(const f16x8*)(bb1 + boff2);
            const int arow = p*12 + mg*16 + l15;
            const int abyte0 = arow*128 + (((0 + g) ^ (arow & 7)) << 4);
            const int abyte1 = arow*128 + (((4 + g) ^ (arow & 7)) << 4);
            f16x8 ah0 = *(const f16x8*)(lds + EHOFF + abyte0);
            f16x8 ah1 = *(const f16x8*)(lds + EHOFF + abyte1);
            __builtin_amdgcn_s_setprio(1);
            mv[0] = __builtin_amdgcn_mfma_f32_16x16x32_f16(ah0, b00, mv[0], 0, 0, 0);
            mv[1] = __builtin_amdgcn_mfma_f32_16x16x32_f16(ah0, b01, mv[1], 0, 0, 0);
            mv[2] = __builtin_amdgcn_mfma_f32_16x16x32_f16(ah0, b02, mv[2], 0, 0, 0);
            mv[0] = __builtin_amdgcn_mfma_f32_16x16x32_f16(ah1, b10, mv[0], 0, 0, 0);
            mv[1] = __builtin_amdgcn_mfma_f32_16x16x32_f16(ah1, b11, mv[1], 0, 0, 0);
            mv[2] = __builtin_amdgcn_mfma_f32_16x16x32_f16(ah1, b12, mv[2], 0, 0, 0);
            if (dual) {
                f16x8 al0 = *(const f16x8*)(lds + ELOFF + abyte0);
                f16x8 al1 = *(const f16x8*)(lds + ELOFF + abyte1);
                mv[0] = __builtin_amdgcn_mfma_f32_16x16x32_f16(al0, b00, mv[0], 0, 0, 0);
                mv[1] = __builtin_amdgcn_mfma_f32_16x16x32_f16(al0, b01, mv[1], 0, 0, 0);
                mv[2] = __builtin_amdgcn_mfma_f32_16x16x32_f16(al0, b02, mv[2], 0, 0, 0);
                mv[0] = __builtin_amdgcn_mfma_f32_16x16x32_f16(al1, b10, mv[0], 0, 0, 0);
                mv[1] = __builtin_amdgcn_mfma_f32_16x16x32_f16(al1, b11, mv[1], 0, 0, 0);
                mv[2] = __builtin_amdgcn_mfma_f32_16x16x32_f16(al1, b12, mv[2], 0, 0, 0);
            }
            __builtin_amdgcn_s_setprio(0);
        }
    }
    // fold v=6
    #pragma unroll
    for (int u = 0; u < 5; ++u) {
        const float a = ATc[u][6];
        if (a != 0.f) {
            #pragma unroll
            for (int fi = 0; fi < 3; ++fi) yu[u][fi] += a * mv[fi];
        }
    }

    WAITL(); SBAR();   // all LDS reads done; reuse LDS for epilogue

    // ---- epilogue: quantize + transpose via LDS, coalesced writes ----
    const float denom = 120.f * sfp[0];
    float av[3], bt3[3];
    #pragma unroll
    for (int fi = 0; fi < 3; ++fi) {
        int o = ng*48 + fi*16 + l15;
        av[fi]  = alpha[o];
        bt3[fi] = rintf(beta[o] * sop[0]);
    }
    float* ldsf = (float*)lds;    // [192][61]
    #pragma unroll
    for (int klocal = 0; klocal < 4; ++klocal) {
        #pragma unroll
        for (int q = 0; q < 4; ++q) {
            int m = mg*16 + g*4 + q;
            if (m / 12 == klocal) {
                int t = m - klocal*12;
                #pragma unroll
                for (int fi = 0; fi < 3; ++fi) {
                    int o = ng*48 + fi*16 + l15;
                    #pragma unroll
                    for (int u = 0; u < 5; ++u) {
                        float yv = yu[u][fi][q];
                        yv = rintf(yv / denom);
                        yv = rintf(av[fi]*yv) + bt3[fi];
                        yv = rintf(yv);
                        yv = fminf(fmaxf(yv, -128.f), 127.f);
                        yv = fmaxf(yv, 0.f);
                        ldsf[o*61 + t*5 + u] = yv;
                    }
                }
            }
        }
        __syncthreads();
        #pragma unroll
        for (int i = 0; i < 14; ++i) {
            int idx2 = i*768 + tid;            // < 10752 = 192*56
            int o = idx2 / 56, col = idx2 - o*56;
            out[(((size_t)(n*COUT + o))*HWD + (k0 + klocal))*HWD + col] = ldsf[o*61 + col];
        }
        __syncthreads();
    }
}

extern "C" void kernel_launch(void* const* d_in, const int* in_sizes, int n_in,
                              void* d_out, int out_size, void* d_ws, size_t ws_size,
                              hipStream_t stream) {
    const float* x      = (const float*)d_in[0];
    const float* weight = (const float*)d_in[1];
    const float* alpha  = (const float*)d_in[2];
    const float* beta   = (const float*)d_in[3];
    const float* sf     = (const float*)d_in[4];
    const float* so     = (const float*)d_in[5];
    float* out = (float*)d_out;

    float* ws_bt = (float*)((char*)d_ws + WS_BT_OFF);
    _Float16* Wp = (_Float16*)((char*)d_ws + WS_W_OFF);

    (void)hipFuncSetAttribute((const void*)main_kernel,
                              hipFuncAttributeMaxDynamicSharedMemorySize, LDS_TOTAL);

    compute_bt_kernel<<<1, 64, 0, stream>>>(ws_bt);
    wt16_kernel<<<(7*COUT*3*CIN + 255)/256, 256, 0, stream>>>(weight, Wp);
    main_kernel<<<dim3(NKQ, NBATCH), 768, LDS_TOTAL, stream>>>(x, Wp, ws_bt, alpha, beta, sf, so, out);
}

// Round 6
// 81.393 us; speedup vs baseline: 1.2741x; 1.2741x over previous
//
#include <hip/hip_runtime.h>
#include <math.h>

typedef _Float16 f16x8 __attribute__((ext_vector_type(8)));
typedef float f32x4 __attribute__((ext_vector_type(4)));
typedef unsigned int u32;
typedef unsigned long long u64;

#define NBATCH 32
#define CIN    64
#define COUT   192
#define HWD    56
#define KR     4
#define NKQ    14

// ---- LDS layout (dynamic, 92160 B) ----
#define EHOFF   0              // 72 rows * 128 B
#define ELOFF   9216
#define BOFF    18432          // 6 bufs * 12288
#define BBUF    12288
#define XOFF    18432          // overlaps B ring; consumed before first STAGE
#define XSTRIDE 88
#define LDS_TOTAL 92160

// ws layout
#define WS_BT_OFF 0
#define WS_W_OFF  1024

#define SBAR()  do { __builtin_amdgcn_s_barrier(); asm volatile("" ::: "memory"); } while(0)
#define WAITL() asm volatile("s_waitcnt lgkmcnt(0)" ::: "memory")
#define WAITV4() asm volatile("s_waitcnt vmcnt(4) lgkmcnt(0)" ::: "memory")
#define WAITV2() asm volatile("s_waitcnt vmcnt(2) lgkmcnt(0)" ::: "memory")
#define WAITV0() asm volatile("s_waitcnt vmcnt(0) lgkmcnt(0)" ::: "memory")

// ---------------- Kernel 1: wave-parallel Householder QR (f64) + fp16-range flag ----------------
__device__ __forceinline__ double wsum(double v) {
    #pragma unroll
    for (int m = 32; m >= 1; m >>= 1) v += __shfl_xor(v, m);
    return v;
}

__global__ void compute_bt_kernel(float* __restrict__ bt) {
    const int lane = threadIdx.x;
    const double ATd[5][7] = {
        {1,1,1,1,1,1,0},{0,1,-1,2,-2,3,0},{0,1,1,4,4,9,0},{0,1,-1,8,-8,27,0},{0,1,1,16,16,81,1}};
    const double pts[6] = {0.0,1.0,-1.0,2.0,-2.0,3.0};

    double Mr[7], Tr[7];
    #pragma unroll
    for (int c = 0; c < 7; ++c) { Mr[c] = 0.0; Tr[c] = 0.0; }
    if (lane < 15) {
        const int p = lane / 5, u = lane % 5;
        #pragma unroll
        for (int v = 0; v < 7; ++v) {
            double gg = (v < 6) ? ((p == 0) ? 1.0 : (p == 1) ? pts[v] : pts[v]*pts[v])
                                : ((p == 2) ? 1.0 : 0.0);
            Mr[v] = ATd[u][v] * gg;
        }
        #pragma unroll
        for (int c = 0; c < 7; ++c) Tr[c] = (c == u + p) ? 1.0 : 0.0;
    }

    #pragma unroll
    for (int j = 0; j < 7; ++j) {
        double mj = Mr[j];
        double sig = wsum((lane >= j && lane < 15) ? mj*mj : 0.0);
        double nrm = sqrt(sig);
        double ajj = __shfl(Mr[j], j);
        double alpha = (ajj > 0.0) ? -nrm : nrm;
        double vi = 0.0;
        if (lane == j) vi = ajj - alpha;
        else if (lane > j && lane < 15) vi = mj;
        double vtv = sig - 2.0*alpha*ajj + alpha*alpha;
        double tau = (vtv > 1e-300) ? (2.0 / vtv) : 0.0;
        #pragma unroll
        for (int c = 0; c < 7; ++c) {
            if (c >= j) {
                double s = wsum(vi * Mr[c]) * tau;
                Mr[c] -= s * vi;
            }
        }
        #pragma unroll
        for (int c = 0; c < 7; ++c) {
            double s = wsum(vi * Tr[c]) * tau;
            Tr[c] -= s * vi;
        }
        if (lane == j) Mr[j] = alpha;
        if (lane > j)  Mr[j] = 0.0;
    }

    __shared__ double Rs[7][7], Ts[7][7];
    if (lane < 7) {
        #pragma unroll
        for (int c = 0; c < 7; ++c) { Rs[lane][c] = Mr[c]; Ts[lane][c] = Tr[c]; }
    }
    __syncthreads();
    const int cc = (lane < 7) ? lane : 0;
    double xs[7];
    #pragma unroll
    for (int i = 6; i >= 0; --i) {
        double s = Ts[i][cc];
        #pragma unroll
        for (int k2 = 6; k2 > i; --k2) s -= Rs[i][k2] * xs[k2];
        xs[i] = s / Rs[i][i];
    }
    if (lane < 7) {
        #pragma unroll
        for (int i = 0; i < 7; ++i) bt[i*7 + lane] = (float)xs[i];
    }
    // fp16-single-plane feasibility: max_v sum_w |BT[v][w]| * 128 <= 2048 ?
    double rs[7];
    #pragma unroll
    for (int v = 0; v < 7; ++v)
        rs[v] = wsum((lane < 7) ? fabs(xs[v]) : 0.0);
    if (lane == 0) {
        double mb = 0.0;
        #pragma unroll
        for (int v = 0; v < 7; ++v) mb = fmax(mb, rs[v]);
        bt[49] = (mb * 128.0 <= 2048.0) ? 1.f : 0.f;
    }
}

// ---------------- Kernel 2: weight transform -> fp16 W[v][o][r][c] ----------------
__global__ void wt16_kernel(const float* __restrict__ w, _Float16* __restrict__ W) {
    int idx = blockIdx.x*256 + threadIdx.x;
    if (idx >= 7*COUT*3*CIN) return;
    int c = idx & 63;
    int r = (idx >> 6) % 3;
    int o = (idx / (64*3)) % COUT;
    int v = idx / (64*3*COUT);
    const float* wp = w + (((size_t)o*CIN + c)*3 + r)*3;
    const float Gf[7][3] = {{1,0,0},{1,1,1},{1,-1,1},{1,2,4},{1,-2,4},{1,3,9},{0,0,1}};
    float val = wp[0]*Gf[v][0] + wp[1]*Gf[v][1] + wp[2]*Gf[v][2];
    val = rintf(val);
    val = fminf(fmaxf(val, -32768.f), 32767.f);   // |val| <= 1664: exact fp16
    W[idx] = (_Float16)val;
}

// ---------------- Kernel 3: fused E-transform + MFMA GEMM + AT + epilogue ----------------
__device__ __forceinline__ void gload16(const void* g, void* l) {
    __builtin_amdgcn_global_load_lds((const __attribute__((address_space(1))) void*)g,
                                     (__attribute__((address_space(3))) void*)l, 16, 0, 0);
}

__global__ __launch_bounds__(768, 3)
void main_kernel(const float* __restrict__ x, const _Float16* __restrict__ W,
                 const float* __restrict__ bt,
                 const float* __restrict__ alpha, const float* __restrict__ beta,
                 const float* __restrict__ sfp, const float* __restrict__ sop,
                 float* __restrict__ out)
{
    extern __shared__ char lds[];
    const int kq = blockIdx.x, n = blockIdx.y, k0 = kq*KR;
    const int tid = threadIdx.x;
    const int wid = tid >> 6, lane = tid & 63, l15 = lane & 15, g = lane >> 4;
    const int mg = wid >> 2, ng = wid & 3;
    const bool dual = (bt[49] < 0.5f);

    const int st_o = tid >> 2, st_q = tid & 3;
    auto STAGE = [&](int S){
        int v = S/6, rem = S%6, rr = rem>>1, ch = rem&1;
        const _Float16* src = W + (((v*COUT + st_o)*3 + rr) << 6) + ch*32 + st_q*8;
        gload16(src, lds + BOFF + (S%6)*BBUF + tid*16);
    };

    // ---- stage x rows (k0-1 .. k0+4) as biased u8 into LDS [6][64][88] (overlaps B ring) ----
    #pragma unroll
    for (int j = 0; j < 7; ++j) {
        int idx = j*768 + tid;                 // < 5376 = 6*64*14
        int krow = idx / 896, rem = idx - krow*896;
        int c = rem / 14, col4 = rem - c*14;
        int xr = k0 + krow - 1;
        u32 bword = 0x80808080u;
        if (xr >= 0 && xr < HWD) {
            const float4 vx = *(const float4*)(x + (((size_t)(n*CIN + c))*HWD + xr)*HWD + col4*4);
            u32 b0 = (u32)(int)(vx.x + 128.f);
            u32 b1 = (u32)(int)(vx.y + 128.f);
            u32 b2 = (u32)(int)(vx.z + 128.f);
            u32 b3 = (u32)(int)(vx.w + 128.f);
            bword = b0 | (b1 << 8) | (b2 << 16) | (b3 << 24);
        }
        *(u32*)(lds + XOFF + (krow*64 + c)*XSTRIDE + 4 + col4*4) = bword;
    }
    #pragma unroll
    for (int jj = 0; jj < 4; ++jj) {           // pads: bytes 0..3 and 60..87 per (krow,c)
        int p = jj*768 + tid;                  // < 3072
        int pr = p >> 3, ws = p & 7;
        int krow = pr >> 6, c = pr & 63;
        int wb = (ws == 0) ? 0 : 56 + ws*4;
        *(u32*)(lds + XOFF + (krow*64 + c)*XSTRIDE + wb) = 0x80808080u;
    }
    __syncthreads();

    // ---- extract per-thread x window (t = wid, c = lane) into 12 PACKED u32 regs ----
    u32 xpA[6], xpB[6];
    {
        const int ofs = (5*wid + 3) & 7;
        const int a0  = (5*wid + 3) & ~7;
        const u32 qsel = (u32)(ofs >> 2);
        const u32 r = (u32)((ofs & 3) * 8);
        #pragma unroll
        for (int krow = 0; krow < 6; ++krow) {
            const char* pb = lds + XOFF + (krow*64 + lane)*XSTRIDE + a0;
            uint2 A2 = *(const uint2*)pb;
            uint2 B2 = *(const uint2*)(pb + 8);
            u32 d0 = A2.x, d1 = A2.y, d2 = B2.x, d3 = B2.y;
            u32 e0 = qsel ? d1 : d0, e1 = qsel ? d2 : d1, e2 = qsel ? d3 : d2;
            u64 lo = (((u64)e1 << 32) | e0) >> r;
            u64 hi = (((u64)e2 << 32) | e1) >> r;
            xpA[krow] = (u32)lo;
            xpB[krow] = (u32)hi;
        }
    }
    __syncthreads();            // X region free; B ring may now be written

    // prologue: fill 6-buffer ring (steps 0..5)
    STAGE(0); STAGE(1); STAGE(2); STAGE(3); STAGE(4); STAGE(5);

    f32x4 mv[3], yu[5][3];
    #pragma unroll
    for (int i = 0; i < 3; ++i) mv[i] = f32x4{0.f,0.f,0.f,0.f};
    #pragma unroll
    for (int u = 0; u < 5; ++u)
        #pragma unroll
        for (int i = 0; i < 3; ++i) yu[u][i] = f32x4{0.f,0.f,0.f,0.f};

    const float ATc[5][7] = {
        {1,1,1,1,1,1,0},{0,1,-1,2,-2,3,0},{0,1,1,4,4,9,0},{0,1,-1,8,-8,27,0},{0,1,1,16,16,81,1}};

    const int boff0 = (ng*48 +  0 + l15)*64 + g*16;
    const int boff1 = (ng*48 + 16 + l15)*64 + g*16;
    const int boff2 = (ng*48 + 32 + l15)*64 + g*16;

    #pragma unroll
    for (int v = 0; v < 7; ++v) {
        // fold previous v's mv into yu (registers only)
        if (v > 0) {
            #pragma unroll
            for (int u = 0; u < 5; ++u) {
                const float a = ATc[u][v-1];
                if (a != 0.f) {
                    #pragma unroll
                    for (int fi = 0; fi < 3; ++fi) yu[u][fi] += a * mv[fi];
                }
            }
            #pragma unroll
            for (int fi = 0; fi < 3; ++fi) mv[fi] = f32x4{0.f,0.f,0.f,0.f};
        }

        SBAR();   // pre-E: all waves' reads of previous v consumed pre-barrier

        // E-compute for this v: rows krow*12 + wid, col = lane (unpack bytes on the fly)
        {
            const float b0 = bt[v*7+0], b1 = bt[v*7+1], b2 = bt[v*7+2], b3 = bt[v*7+3];
            const float b4 = bt[v*7+4], b5 = bt[v*7+5], b6 = bt[v*7+6];
            const float einit = -128.f * (b0+b1+b2+b3+b4+b5+b6);
            #pragma unroll
            for (int krow = 0; krow < 6; ++krow) {
                const u32 Aw = xpA[krow], Bw = xpB[krow];
                float e = einit;
                e = fmaf(b0, (float)(Aw & 255u),         e);
                e = fmaf(b1, (float)((Aw >> 8) & 255u),  e);
                e = fmaf(b2, (float)((Aw >> 16) & 255u), e);
                e = fmaf(b3, (float)(Aw >> 24),          e);
                e = fmaf(b4, (float)(Bw & 255u),         e);
                e = fmaf(b5, (float)((Bw >> 8) & 255u),  e);
                e = fmaf(b6, (float)((Bw >> 16) & 255u), e);
                e = rintf(e);
                e = fminf(fmaxf(e, -32768.f), 32767.f);
                const int row = krow*12 + wid;
                const int sbyte = ((((lane>>3) ^ (row&7)) << 4) | ((lane&7) << 1));
                if (dual) {
                    float ehs = rintf(e * (1.f/2048.f)) * 2048.f;
                    float el  = e - ehs;
                    *(_Float16*)(lds + EHOFF + row*128 + sbyte) = (_Float16)ehs;
                    *(_Float16*)(lds + ELOFF + row*128 + sbyte) = (_Float16)el;
                } else {
                    *(_Float16*)(lds + EHOFF + row*128 + sbyte) = (_Float16)e;
                }
            }
        }

        // 3 fat phases (K=64 each, processed as two K=32 halves) for this v
        #pragma unroll
        for (int p = 0; p < 3; ++p) {
            const int S = v*6 + 2*p;
            if (S == 0)       { WAITV4(); }
            else if (S == 40) { WAITV0(); }
            else              { WAITV2(); }
            SBAR();
            if (S >= 2) {
                if (S + 4 <= 41) STAGE(S + 4);
                if (S + 5 <= 41) STAGE(S + 5);
            }
            const int arow = p*12 + mg*16 + l15;
            // ---- K-half 0 ----
            {
                const char* bb = lds + BOFF + (S % 6)*BBUF;
                f16x8 bf0 = *(const f16x8*)(bb + boff0);
                f16x8 bf1 = *(const f16x8*)(bb + boff1);
                f16x8 bf2 = *(const f16x8*)(bb + boff2);
                const int abyte = arow*128 + (((0 + g) ^ (arow & 7)) << 4);
                f16x8 ah = *(const f16x8*)(lds + EHOFF + abyte);
                __builtin_amdgcn_s_setprio(1);
                mv[0] = __builtin_amdgcn_mfma_f32_16x16x32_f16(ah, bf0, mv[0], 0, 0, 0);
                mv[1] = __builtin_amdgcn_mfma_f32_16x16x32_f16(ah, bf1, mv[1], 0, 0, 0);
                mv[2] = __builtin_amdgcn_mfma_f32_16x16x32_f16(ah, bf2, mv[2], 0, 0, 0);
                if (dual) {
                    f16x8 al = *(const f16x8*)(lds + ELOFF + abyte);
                    mv[0] = __builtin_amdgcn_mfma_f32_16x16x32_f16(al, bf0, mv[0], 0, 0, 0);
                    mv[1] = __builtin_amdgcn_mfma_f32_16x16x32_f16(al, bf1, mv[1], 0, 0, 0);
                    mv[2] = __builtin_amdgcn_mfma_f32_16x16x32_f16(al, bf2, mv[2], 0, 0, 0);
                }
                __builtin_amdgcn_s_setprio(0);
            }
            // ---- K-half 1 ----
            {
                const char* bb = lds + BOFF + ((S + 1) % 6)*BBUF;
                f16x8 bf0 = *(const f16x8*)(bb + boff0);
                f16x8 bf1 = *(const f16x8*)(bb + boff1);
                f16x8 bf2 = *(const f16x8*)(bb + boff2);
                const int abyte = arow*128 + (((4 + g) ^ (arow & 7)) << 4);
                f16x8 ah = *(const f16x8*)(lds + EHOFF + abyte);
                __builtin_amdgcn_s_setprio(1);
                mv[0] = __builtin_amdgcn_mfma_f32_16x16x32_f16(ah, bf0, mv[0], 0, 0, 0);
                mv[1] = __builtin_amdgcn_mfma_f32_16x16x32_f16(ah, bf1, mv[1], 0, 0, 0);
                mv[2] = __builtin_amdgcn_mfma_f32_16x16x32_f16(ah, bf2, mv[2], 0, 0, 0);
                if (dual) {
                    f16x8 al = *(const f16x8*)(lds + ELOFF + abyte);
                    mv[0] = __builtin_amdgcn_mfma_f32_16x16x32_f16(al, bf0, mv[0], 0, 0, 0);
                    mv[1] = __builtin_amdgcn_mfma_f32_16x16x32_f16(al, bf1, mv[1], 0, 0, 0);
                    mv[2] = __builtin_amdgcn_mfma_f32_16x16x32_f16(al, bf2, mv[2], 0, 0, 0);
                }
                __builtin_amdgcn_s_setprio(0);
            }
        }
    }
    // fold v=6
    #pragma unroll
    for (int u = 0; u < 5; ++u) {
        const float a = ATc[u][6];
        if (a != 0.f) {
            #pragma unroll
            for (int fi = 0; fi < 3; ++fi) yu[u][fi] += a * mv[fi];
        }
    }

    WAITL(); SBAR();   // all LDS reads done; reuse LDS for epilogue

    // ---- epilogue: quantize to u8 in LDS, then one fully-coalesced aligned pass ----
    const float rdenom = 1.f / (120.f * sfp[0]);
    float av[3], bt3[3];
    #pragma unroll
    for (int fi = 0; fi < 3; ++fi) {
        int o = ng*48 + fi*16 + l15;
        av[fi]  = alpha[o];
        bt3[fi] = rintf(beta[o] * sop[0]);
    }
    unsigned char* ldsb = (unsigned char*)lds;   // [192][224] u8 = 43008 B
    #pragma unroll
    for (int q = 0; q < 4; ++q) {
        const int m = mg*16 + g*4 + q;           // 0..47
        const int k = m / 12, t = m - k*12;
        #pragma unroll
        for (int fi = 0; fi < 3; ++fi) {
            const int o = ng*48 + fi*16 + l15;
            #pragma unroll
            for (int u = 0; u < 5; ++u) {
                const int col = t*5 + u;
                if (col < HWD) {
                    float yv = yu[u][fi][q];
                    yv = rintf(yv * rdenom);
                    yv = rintf(av[fi]*yv) + bt3[fi];
                    yv = rintf(yv);
                    yv = fminf(fmaxf(yv, -128.f), 127.f);
                    yv = fmaxf(yv, 0.f);
                    ldsb[o*224 + k*56 + col] = (unsigned char)(int)yv;
                }
            }
        }
    }
    __syncthreads();
    float* ob = out + ((size_t)(n*COUT))*3136 + k0*56;
    #pragma unroll
    for (int it = 0; it < 14; ++it) {
        int i = it*768 + tid;                    // < 10752 = 192*56 quads
        int o = i / 56, q4 = i - o*56;
        u32 wbits = *(const u32*)(ldsb + o*224 + q4*4);
        float4 f;
        f.x = (float)(wbits & 255u);
        f.y = (float)((wbits >> 8) & 255u);
        f.z = (float)((wbits >> 16) & 255u);
        f.w = (float)(wbits >> 24);
        *(float4*)(ob + (size_t)o*3136 + q4*4) = f;
    }
}

extern "C" void kernel_launch(void* const* d_in, const int* in_sizes, int n_in,
                              void* d_out, int out_size, void* d_ws, size_t ws_size,
                              hipStream_t stream) {
    const float* x      = (const float*)d_in[0];
    const float* weight = (const float*)d_in[1];
    const float* alpha  = (const float*)d_in[2];
    const float* beta   = (const float*)d_in[3];
    const float* sf     = (const float*)d_in[4];
    const float* so     = (const float*)d_in[5];
    float* out = (float*)d_out;

    float* ws_bt = (float*)((char*)d_ws + WS_BT_OFF);
    _Float16* Wp = (_Float16*)((char*)d_ws + WS_W_OFF);

    (void)hipFuncSetAttribute((const void*)main_kernel,
                              hipFuncAttributeMaxDynamicSharedMemorySize, LDS_TOTAL);

    compute_bt_kernel<<<1, 64, 0, stream>>>(ws_bt);
    wt16_kernel<<<(7*COUT*3*CIN + 255)/256, 256, 0, stream>>>(weight, Wp);
    main_kernel<<<dim3(NKQ, NBATCH), 768, LDS_TOTAL, stream>>>(x, Wp, ws_bt, alpha, beta, sf, so, out);
}